// Round 3
// baseline (465.893 us; speedup 1.0000x reference)
//
#include <hip/hip_runtime.h>

// CausalSelfAttention: B=8, S=2048, D=512, fp32 in/out, Q=K=V=x, no scale.
// Round 6: NO LDS staging — direct-from-L2 register fragments.
//   r4/r5 post-mortem: every LDS-coupled pipeline variant (runtime-indexed
//   dbuf, static dbuf + raw barriers) either forced compiler vmcnt(0) drains
//   into the tile loop or spilled (r5: VGPR 256 + scratch traffic in
//   FETCH/WRITE). Root fix: the prepass stores K/V in fragment order, so a
//   plain global load at base+lane*8 IS the MFMA B-fragment. Drop LDS staging
//   entirely:
//     - 1024 blocks x 64 thr: one wave owns 16 Q-rows, full D. No barriers,
//       no cross-wave coupling, no K/V LDS traffic.
//     - bat = bid&7 -> all blocks of batch b land on XCD b (round-robin),
//       whose 4MiB L2 exactly holds that batch's Kf+Vf (2+2 MiB). K/V loads
//       are L2-resident, 1KB/instruction coalesced.
//     - idx=bid>>3, j=idx>>5, k=idx&31; rowgroup map {2k,127-2k,2k+1,126-2k}
//       gives every CU exactly 130 tiles of work (perfect static balance),
//       4 co-resident waves/CU (1/SIMD), same batch -> L1 sharing.
//     - softmax in registers (DPP), P transpose via 1.25KB wave-private LDS.
//     - T5 s_setprio(1) around MFMA clusters (attn-positive, m191 regime:
//       independent 1-wave blocks).
// ws: [0,16MiB) Kf, [16MiB,32MiB) Vf.

#define S_LEN 2048
#define D_DIM 512
#define BATCH_ELEMS 1048576  // 2 MiB bf16 per batch per array

typedef short s16x8 __attribute__((ext_vector_type(8)));
typedef float f32x4 __attribute__((ext_vector_type(4)));

__device__ __forceinline__ unsigned short f2b_rne(float f) {
  unsigned int u = __float_as_uint(f);
  return (unsigned short)((u + 0x7FFFu + ((u >> 16) & 1u)) >> 16);
}
__device__ __forceinline__ unsigned short f2b_fast(float f) {
  return (unsigned short)((__float_as_uint(f) + 0x8000u) >> 16);
}

template <int CTRL>
__device__ __forceinline__ float dppf(float x) {
  return __uint_as_float((unsigned)__builtin_amdgcn_update_dpp(
      0, (int)__float_as_uint(x), CTRL, 0xF, 0xF, true));
}
__device__ __forceinline__ float red16_max(float v) {
  v = fmaxf(v, dppf<0xB1>(v));   // xor 1
  v = fmaxf(v, dppf<0x4E>(v));   // xor 2
  v = fmaxf(v, dppf<0x124>(v));  // row_ror:4
  v = fmaxf(v, dppf<0x128>(v));  // row_ror:8
  return v;
}
__device__ __forceinline__ float red16_sum(float v) {
  v += dppf<0xB1>(v);
  v += dppf<0x4E>(v);
  v += dppf<0x124>(v);
  v += dppf<0x128>(v);
  return v;
}

// ---------------------------------------------------------------------------
// Prepass: pack x into Kf and Vf fragment order. 2048 blocks x 256 thr,
// 64x64 tile per block. A = [s][d] bf16, T = [d][s] bf16 (stride 72, 16B-al).
//   Kf[b][kg:128][db:16][lane:64][8]  elem = x[b][16*kg+l15][32*db+8*quad+j]
//   Vf[b][dg:32][kb:64][lane:64][8]   elem = x[b][32*kb+8*quad+j][16*dg+l15]
// ---------------------------------------------------------------------------
__global__ void pack_kernel(const float* __restrict__ x,
                            unsigned short* __restrict__ Kf,
                            unsigned short* __restrict__ Vf) {
  __shared__ unsigned short A[64 * 72];
  __shared__ unsigned short T[64 * 72];
  const int bid = blockIdx.x;
  const int b = bid >> 8, rem = bid & 255;
  const int s0 = (rem >> 3) * 64, d0 = (rem & 7) * 64;
  const int tid = threadIdx.x;

  // pass 1: load + convert, fill A[s][d]
  #pragma unroll
  for (int it = 0; it < 2; ++it) {
    int slot = it * 256 + tid;          // 0..511
    int row = slot >> 3, c = slot & 7;  // row 0..63, 8-col group
    const float* src = x + ((size_t)(b * S_LEN + s0 + row)) * D_DIM + d0 + c * 8;
    const float4 v0 = *(const float4*)(src);
    const float4 v1 = *(const float4*)(src + 4);
    s16x8 o;
    o[0] = (short)f2b_rne(v0.x); o[1] = (short)f2b_rne(v0.y);
    o[2] = (short)f2b_rne(v0.z); o[3] = (short)f2b_rne(v0.w);
    o[4] = (short)f2b_rne(v1.x); o[5] = (short)f2b_rne(v1.y);
    o[6] = (short)f2b_rne(v1.z); o[7] = (short)f2b_rne(v1.w);
    *(s16x8*)&A[row * 72 + c * 8] = o;
  }
  __syncthreads();

  // pass 2: transpose A -> T in 4x4 micro-blocks (vector b64 ops)
  {
    int sr = tid >> 4, sc = tid & 15;
    ushort4 a0 = *(const ushort4*)&A[(4 * sr + 0) * 72 + 4 * sc];
    ushort4 a1 = *(const ushort4*)&A[(4 * sr + 1) * 72 + 4 * sc];
    ushort4 a2 = *(const ushort4*)&A[(4 * sr + 2) * 72 + 4 * sc];
    ushort4 a3 = *(const ushort4*)&A[(4 * sr + 3) * 72 + 4 * sc];
    ushort4 t0; t0.x = a0.x; t0.y = a1.x; t0.z = a2.x; t0.w = a3.x;
    ushort4 t1; t1.x = a0.y; t1.y = a1.y; t1.z = a2.y; t1.w = a3.y;
    ushort4 t2; t2.x = a0.z; t2.y = a1.z; t2.z = a2.z; t2.w = a3.z;
    ushort4 t3; t3.x = a0.w; t3.y = a1.w; t3.z = a2.w; t3.w = a3.w;
    *(ushort4*)&T[(4 * sc + 0) * 72 + 4 * sr] = t0;
    *(ushort4*)&T[(4 * sc + 1) * 72 + 4 * sr] = t1;
    *(ushort4*)&T[(4 * sc + 2) * 72 + 4 * sr] = t2;
    *(ushort4*)&T[(4 * sc + 3) * 72 + 4 * sr] = t3;
  }
  __syncthreads();

  // pass 3: emit fragment blocks (each 64 consecutive threads write 1KB)
  #pragma unroll
  for (int it = 0; it < 2; ++it) {
    int slot = it * 256 + tid;
    int frag = slot >> 6;               // 0..7
    int lane = slot & 63;
    int l15 = lane & 15, quad = lane >> 4;
    int f1 = frag >> 1, f0 = frag & 1;  // f1: 0..3, f0: 0..1
    // Kf: kgl=f1 (16 rows), dbl=f0 (32 cols)
    {
      s16x8 val = *(const s16x8*)&A[(f1 * 16 + l15) * 72 + f0 * 32 + quad * 8];
      size_t kg = (size_t)(s0 >> 4) + f1, db = (size_t)(d0 >> 5) + f0;
      *(s16x8*)(Kf + (size_t)b * BATCH_ELEMS + (kg * 16 + db) * 512 + lane * 8) = val;
    }
    // Vf: dgl=f1 (16 cols), kbl=f0 (32 rows)
    {
      s16x8 val = *(const s16x8*)&T[(f1 * 16 + l15) * 72 + f0 * 32 + quad * 8];
      size_t dg = (size_t)(d0 >> 4) + f1, kb = (size_t)(s0 >> 5) + f0;
      *(s16x8*)(Vf + (size_t)b * BATCH_ELEMS + (dg * 64 + kb) * 512 + lane * 8) = val;
    }
  }
}

// ---------------------------------------------------------------------------
// Flash attention, one wave per 16-row group, fragments direct from global.
// MFMA 16x16x32 layouts: A[m=l15][k=quad*8+j], B[k=quad*8+j][n=l15],
// C/D: col=l15, row=quad*4+reg.
// ---------------------------------------------------------------------------
__global__ __launch_bounds__(64, 1)
void attn_kernel(const unsigned short* __restrict__ Kf,
                 const unsigned short* __restrict__ Vf,
                 float* __restrict__ out) {
  __shared__ unsigned short Pw[16 * 40];  // wave-private P transpose buffer

  const int bid = blockIdx.x;
  const int bat = bid & 7;                 // == XCD id under round-robin
  const int idx = bid >> 3;                // 0..127
  const int jj = idx >> 5, kk = idx & 31;  // balance map: 130 tiles per CU
  int rg;
  if (jj == 0)      rg = 2 * kk;           // tiles kk+1
  else if (jj == 1) rg = 127 - 2 * kk;     // tiles 64-kk
  else if (jj == 2) rg = 2 * kk + 1;       // tiles kk+1
  else              rg = 126 - 2 * kk;     // tiles 64-kk
  const int q0 = rg * 16;
  const int tmax = rg >> 1;
  const int lane = threadIdx.x;
  const int l15 = lane & 15, quad = lane >> 4;
  const size_t batOff = (size_t)bat * BATCH_ELEMS;

  // Q fragments: rows q0..q0+15, full D (frag-blocks are lane-contiguous)
  s16x8 qf[16];
  {
    const unsigned short* qb = Kf + batOff + ((size_t)rg * 16) * 512 + lane * 8;
    #pragma unroll
    for (int db = 0; db < 16; ++db) qf[db] = *(const s16x8*)(qb + db * 512);
  }

  f32x4 O[32];
  float m[4], l[4];
  #pragma unroll
  for (int n = 0; n < 32; ++n) O[n] = (f32x4){0.f, 0.f, 0.f, 0.f};
  #pragma unroll
  for (int r = 0; r < 4; ++r) { m[r] = -3e38f; l[r] = 0.f; }

  for (int kt = 0; kt <= tmax; ++kt) {
    const unsigned short* kb = Kf + batOff + (size_t)kt * 16384 + lane * 8;
    const unsigned short* vb = Vf + batOff + (size_t)kt * 512 + lane * 8;

    // ---- QK^T: S[16 rows][32 keys], K frags direct from L2 ----
    f32x4 sacc[2];
    sacc[0] = (f32x4){0.f, 0.f, 0.f, 0.f};
    sacc[1] = (f32x4){0.f, 0.f, 0.f, 0.f};
    __builtin_amdgcn_s_setprio(1);
    #pragma unroll
    for (int db = 0; db < 16; ++db) {
      s16x8 k0 = *(const s16x8*)(kb + (size_t)db * 512);
      s16x8 k1 = *(const s16x8*)(kb + (size_t)(16 + db) * 512);
      sacc[0] = __builtin_amdgcn_mfma_f32_16x16x32_bf16(qf[db], k0, sacc[0], 0, 0, 0);
      sacc[1] = __builtin_amdgcn_mfma_f32_16x16x32_bf16(qf[db], k1, sacc[1], 0, 0, 0);
    }
    __builtin_amdgcn_s_setprio(0);

    if (kt == tmax) {  // causal mask on diagonal tile
      #pragma unroll
      for (int kg2 = 0; kg2 < 2; ++kg2)
        #pragma unroll
        for (int r = 0; r < 4; ++r) {
          int key = kt * 32 + kg2 * 16 + l15;
          int row = q0 + quad * 4 + r;
          if (key > row) sacc[kg2][r] = -3e38f;
        }
    }

    // ---- online softmax (registers + DPP) ----
    float mt[4], alpha[4];
    #pragma unroll
    for (int r = 0; r < 4; ++r)
      mt[r] = red16_max(fmaxf(sacc[0][r], sacc[1][r]));
    bool needAny = (mt[0] > m[0]) | (mt[1] > m[1]) | (mt[2] > m[2]) | (mt[3] > m[3]);
    unsigned long long bal = __ballot(needAny);
    if (bal) {
      #pragma unroll
      for (int r = 0; r < 4; ++r) {
        float mn = fmaxf(m[r], mt[r]);
        alpha[r] = __expf(m[r] - mn);
        m[r] = mn;
      }
    } else {
      #pragma unroll
      for (int r = 0; r < 4; ++r) alpha[r] = 1.0f;
    }
    float p[2][4];
    #pragma unroll
    for (int kg2 = 0; kg2 < 2; ++kg2)
      #pragma unroll
      for (int r = 0; r < 4; ++r) p[kg2][r] = __expf(sacc[kg2][r] - m[r]);
    #pragma unroll
    for (int r = 0; r < 4; ++r)
      l[r] = l[r] * alpha[r] + red16_sum(p[0][r] + p[1][r]);

    // ---- P: C-layout -> A-layout via wave-private LDS ----
    #pragma unroll
    for (int kg2 = 0; kg2 < 2; ++kg2)
      #pragma unroll
      for (int r = 0; r < 4; ++r)
        Pw[(quad * 4 + r) * 40 + kg2 * 16 + l15] = f2b_fast(p[kg2][r]);
    s16x8 pa = *(const s16x8*)&Pw[l15 * 40 + quad * 8];

    if (bal) {
      #pragma unroll
      for (int n = 0; n < 32; ++n)
        #pragma unroll
        for (int r = 0; r < 4; ++r) O[n][r] *= alpha[r];
    }

    // ---- PV: O[16 rows][512] += P(16x32) * V(32x512), V direct from L2 ----
    __builtin_amdgcn_s_setprio(1);
    #pragma unroll
    for (int dg = 0; dg < 32; ++dg) {
      s16x8 vf = *(const s16x8*)(vb + (size_t)dg * 32768);
      O[dg] = __builtin_amdgcn_mfma_f32_16x16x32_bf16(pa, vf, O[dg], 0, 0, 0);
    }
    __builtin_amdgcn_s_setprio(0);
  }

  // ---- epilogue ----
  float invl[4];
  #pragma unroll
  for (int r = 0; r < 4; ++r) invl[r] = 1.0f / l[r];
  float* ob = out + ((size_t)(bat * S_LEN + q0)) * D_DIM;
  #pragma unroll
  for (int dg = 0; dg < 32; ++dg)
    #pragma unroll
    for (int r = 0; r < 4; ++r)
      ob[(size_t)(quad * 4 + r) * D_DIM + dg * 16 + l15] = O[dg][r] * invl[r];
}

extern "C" void kernel_launch(void* const* d_in, const int* in_sizes, int n_in,
                              void* d_out, int out_size, void* d_ws, size_t ws_size,
                              hipStream_t stream) {
  (void)in_sizes; (void)n_in; (void)out_size; (void)ws_size;
  const float* x = (const float*)d_in[0];
  float* out = (float*)d_out;
  unsigned short* Kf = (unsigned short*)d_ws;                         // 16 MiB
  unsigned short* Vf = (unsigned short*)((char*)d_ws + (16u << 20));  // 16 MiB
  pack_kernel<<<2048, 256, 0, stream>>>(x, Kf, Vf);
  attn_kernel<<<1024, 64, 0, stream>>>(Kf, Vf, out);
}

// Round 4
// 210.864 us; speedup vs baseline: 2.2094x; 2.2094x over previous
//
#include <hip/hip_runtime.h>

// CausalSelfAttention: B=8, S=2048, D=512, fp32 in/out, Q=K=V=x, no scale.
// Round 7: r0 skeleton (best measured: 164us attn) + 4-way wave split.
//   r4/r5/r6 post-mortem: pipelined staging fought the compiler (drains,
//   spills); direct-L2 MFMA feeding serialized on vmcnt. Revert to r0's
//   single-buffered sync->stage->sync staging and instead attack per-wave
//   serial cost + wave starvation (r0 ran 1 wave/SIMD):
//     - 512 blocks x 256 thr (4 waves). Block = one 32-row rowgroup, same
//       heavy/light sum-65 pairing as r0.
//     - wave pair p (waves 2p,2p+1) owns rows q0+16p..+15. Within pair:
//       wave wip=0 computes QK^T partial over d=0..255, wip=1 over d=256..511
//       (8 frags each); partials summed via 2KB LDS exchange (commutative
//       fp32 add -> both waves hold identical S; softmax duplicated in-pair).
//     - PV split by output cols: wip=0 -> dg 0..15 (cols 0..255), wip=1 ->
//       dg 16..31. O shrinks to 16 f32x4 (64 VGPR). No epilogue merge.
//     - per-wave per-tile: 16 stage loads (was 32), 16+16 ds_read (was 64),
//       16+16 MFMA (was 64). 8 waves/CU = 2/SIMD when both blocks resident.
//   LDS: 32K K + 32K V + 8K exchange + 5K Pw = 77KB -> 2 blocks/CU.
// ws: [0,16MiB) Kf, [16MiB,32MiB) Vf.

#define S_LEN 2048
#define D_DIM 512
#define BATCH_ELEMS 1048576  // 2 MiB bf16 per batch per array

typedef short s16x8 __attribute__((ext_vector_type(8)));
typedef float f32x4 __attribute__((ext_vector_type(4)));

__device__ __forceinline__ unsigned short f2b_rne(float f) {
  unsigned int u = __float_as_uint(f);
  return (unsigned short)((u + 0x7FFFu + ((u >> 16) & 1u)) >> 16);
}
__device__ __forceinline__ unsigned short f2b_fast(float f) {
  return (unsigned short)((__float_as_uint(f) + 0x8000u) >> 16);
}

template <int CTRL>
__device__ __forceinline__ float dppf(float x) {
  return __uint_as_float((unsigned)__builtin_amdgcn_update_dpp(
      0, (int)__float_as_uint(x), CTRL, 0xF, 0xF, true));
}
__device__ __forceinline__ float red16_max(float v) {
  v = fmaxf(v, dppf<0xB1>(v));   // xor 1
  v = fmaxf(v, dppf<0x4E>(v));   // xor 2
  v = fmaxf(v, dppf<0x124>(v));  // row_ror:4
  v = fmaxf(v, dppf<0x128>(v));  // row_ror:8
  return v;
}
__device__ __forceinline__ float red16_sum(float v) {
  v += dppf<0xB1>(v);
  v += dppf<0x4E>(v);
  v += dppf<0x124>(v);
  v += dppf<0x128>(v);
  return v;
}

// ---------------------------------------------------------------------------
// Prepass: pack x into Kf and Vf fragment order. 2048 blocks x 256 thr,
// 64x64 tile per block. A = [s][d] bf16, T = [d][s] bf16 (stride 72, 16B-al).
//   Kf[b][kg:128][db:16][lane:64][8]  elem = x[b][16*kg+l15][32*db+8*quad+j]
//   Vf[b][dg:32][kb:64][lane:64][8]   elem = x[b][32*kb+8*quad+j][16*dg+l15]
// ---------------------------------------------------------------------------
__global__ void pack_kernel(const float* __restrict__ x,
                            unsigned short* __restrict__ Kf,
                            unsigned short* __restrict__ Vf) {
  __shared__ unsigned short A[64 * 72];
  __shared__ unsigned short T[64 * 72];
  const int bid = blockIdx.x;
  const int b = bid >> 8, rem = bid & 255;
  const int s0 = (rem >> 3) * 64, d0 = (rem & 7) * 64;
  const int tid = threadIdx.x;

  // pass 1: load + convert, fill A[s][d]
  #pragma unroll
  for (int it = 0; it < 2; ++it) {
    int slot = it * 256 + tid;          // 0..511
    int row = slot >> 3, c = slot & 7;  // row 0..63, 8-col group
    const float* src = x + ((size_t)(b * S_LEN + s0 + row)) * D_DIM + d0 + c * 8;
    const float4 v0 = *(const float4*)(src);
    const float4 v1 = *(const float4*)(src + 4);
    s16x8 o;
    o[0] = (short)f2b_rne(v0.x); o[1] = (short)f2b_rne(v0.y);
    o[2] = (short)f2b_rne(v0.z); o[3] = (short)f2b_rne(v0.w);
    o[4] = (short)f2b_rne(v1.x); o[5] = (short)f2b_rne(v1.y);
    o[6] = (short)f2b_rne(v1.z); o[7] = (short)f2b_rne(v1.w);
    *(s16x8*)&A[row * 72 + c * 8] = o;
  }
  __syncthreads();

  // pass 2: transpose A -> T in 4x4 micro-blocks (vector b64 ops)
  {
    int sr = tid >> 4, sc = tid & 15;
    ushort4 a0 = *(const ushort4*)&A[(4 * sr + 0) * 72 + 4 * sc];
    ushort4 a1 = *(const ushort4*)&A[(4 * sr + 1) * 72 + 4 * sc];
    ushort4 a2 = *(const ushort4*)&A[(4 * sr + 2) * 72 + 4 * sc];
    ushort4 a3 = *(const ushort4*)&A[(4 * sr + 3) * 72 + 4 * sc];
    ushort4 t0; t0.x = a0.x; t0.y = a1.x; t0.z = a2.x; t0.w = a3.x;
    ushort4 t1; t1.x = a0.y; t1.y = a1.y; t1.z = a2.y; t1.w = a3.y;
    ushort4 t2; t2.x = a0.z; t2.y = a1.z; t2.z = a2.z; t2.w = a3.z;
    ushort4 t3; t3.x = a0.w; t3.y = a1.w; t3.z = a2.w; t3.w = a3.w;
    *(ushort4*)&T[(4 * sc + 0) * 72 + 4 * sr] = t0;
    *(ushort4*)&T[(4 * sc + 1) * 72 + 4 * sr] = t1;
    *(ushort4*)&T[(4 * sc + 2) * 72 + 4 * sr] = t2;
    *(ushort4*)&T[(4 * sc + 3) * 72 + 4 * sr] = t3;
  }
  __syncthreads();

  // pass 3: emit fragment blocks (each 64 consecutive threads write 1KB)
  #pragma unroll
  for (int it = 0; it < 2; ++it) {
    int slot = it * 256 + tid;
    int frag = slot >> 6;               // 0..7
    int lane = slot & 63;
    int l15 = lane & 15, quad = lane >> 4;
    int f1 = frag >> 1, f0 = frag & 1;  // f1: 0..3, f0: 0..1
    // Kf: kgl=f1 (16 rows), dbl=f0 (32 cols)
    {
      s16x8 val = *(const s16x8*)&A[(f1 * 16 + l15) * 72 + f0 * 32 + quad * 8];
      size_t kg = (size_t)(s0 >> 4) + f1, db = (size_t)(d0 >> 5) + f0;
      *(s16x8*)(Kf + (size_t)b * BATCH_ELEMS + (kg * 16 + db) * 512 + lane * 8) = val;
    }
    // Vf: dgl=f1 (16 cols), kbl=f0 (32 rows)
    {
      s16x8 val = *(const s16x8*)&T[(f1 * 16 + l15) * 72 + f0 * 32 + quad * 8];
      size_t dg = (size_t)(d0 >> 4) + f1, kb = (size_t)(s0 >> 5) + f0;
      *(s16x8*)(Vf + (size_t)b * BATCH_ELEMS + (dg * 64 + kb) * 512 + lane * 8) = val;
    }
  }
}

// ---------------------------------------------------------------------------
// Flash attention: 4 waves/block, split-D QK^T (partial exchange), split-col
// PV. MFMA 16x16x32 layouts: A[m=l15][k=quad*8+j], B[k=quad*8+j][n=l15],
// C/D: col=l15, row=quad*4+reg.
// ---------------------------------------------------------------------------
__global__ __launch_bounds__(256, 2)
void attn_kernel(const unsigned short* __restrict__ Kf,
                 const unsigned short* __restrict__ Vf,
                 float* __restrict__ out) {
  __shared__ unsigned short ldsK[16384];  // 32 frag-blocks (kg2*16+db)*512+lane*8
  __shared__ unsigned short ldsV[16384];  // 32 frag-blocks dg*512+lane*8
  __shared__ float Xc[4][512];            // per-wave partial S (16x32 f32)
  __shared__ unsigned short Pw[4][16 * 40];

  const int bid = blockIdx.x;
  const int bat = bid & 7;
  const int t = (bid < 256) ? (63 - (bid >> 3)) : ((bid - 256) >> 3);
  const int q0 = t * 32;
  const int tid = threadIdx.x;
  const int w = tid >> 6;       // 0..3
  const int pairIdx = w >> 1;   // which 16-row half of the 32-row group
  const int wip = w & 1;        // which D-half (QK) / col-half (PV)
  const int lane = tid & 63;
  const int l15 = lane & 15, quad = lane >> 4;
  const size_t batOff = (size_t)bat * BATCH_ELEMS;

  // Q fragments: rows q0+16*pairIdx..+15, d-half wip (db = wip*8 + i)
  s16x8 qf[8];
  {
    const unsigned short* qb =
        Kf + batOff + ((size_t)(2 * t + pairIdx) * 16 + wip * 8) * 512 + lane * 8;
    #pragma unroll
    for (int i = 0; i < 8; ++i) qf[i] = *(const s16x8*)(qb + i * 512);
  }

  f32x4 O[16];
  float m[4], l[4];
  #pragma unroll
  for (int n = 0; n < 16; ++n) O[n] = (f32x4){0.f, 0.f, 0.f, 0.f};
  #pragma unroll
  for (int r = 0; r < 4; ++r) { m[r] = -3e38f; l[r] = 0.f; }

  for (int kt = 0; kt <= t; ++kt) {
    __syncthreads();  // previous tile's LDS reads complete before overwrite
    // ---- stage K tile (32KB) + V tile (32KB), split across 4 waves ----
    {
      const unsigned short* ks =
          Kf + batOff + (size_t)kt * 16384 + (size_t)(w * 8) * 512 + lane * 8;
      #pragma unroll
      for (int i = 0; i < 8; ++i) {
        __builtin_amdgcn_global_load_lds(
            (const __attribute__((address_space(1))) unsigned int*)(ks + i * 512),
            (__attribute__((address_space(3))) unsigned int*)&ldsK[(w * 8 + i) * 512],
            16, 0, 0);
      }
      const unsigned short* vs = Vf + batOff + (size_t)kt * 512 + lane * 8;
      #pragma unroll
      for (int i = 0; i < 8; ++i) {
        int dg = w * 8 + i;
        __builtin_amdgcn_global_load_lds(
            (const __attribute__((address_space(1))) unsigned int*)(vs + (size_t)dg * 32768),
            (__attribute__((address_space(3))) unsigned int*)&ldsV[dg * 512],
            16, 0, 0);
      }
    }
    __syncthreads();  // staging visible (implicit vmcnt drain)

    // ---- QK^T partial over this wave's D-half: S_half[16 rows][32 keys] ----
    f32x4 sacc[2];
    sacc[0] = (f32x4){0.f, 0.f, 0.f, 0.f};
    sacc[1] = (f32x4){0.f, 0.f, 0.f, 0.f};
    __builtin_amdgcn_s_setprio(1);
    #pragma unroll
    for (int i = 0; i < 8; ++i) {
      int db = wip * 8 + i;
      s16x8 k0 = *(const s16x8*)&ldsK[db * 512 + lane * 8];
      s16x8 k1 = *(const s16x8*)&ldsK[(16 + db) * 512 + lane * 8];
      sacc[0] = __builtin_amdgcn_mfma_f32_16x16x32_bf16(qf[i], k0, sacc[0], 0, 0, 0);
      sacc[1] = __builtin_amdgcn_mfma_f32_16x16x32_bf16(qf[i], k1, sacc[1], 0, 0, 0);
    }
    __builtin_amdgcn_s_setprio(0);

    // ---- exchange partials within the pair (w ^ 1), sum -> full S ----
    *(f32x4*)&Xc[w][lane * 4] = sacc[0];
    *(f32x4*)&Xc[w][256 + lane * 4] = sacc[1];
    __syncthreads();  // publish partials (lgkm drain)
    {
      f32x4 pc0 = *(const f32x4*)&Xc[w ^ 1][lane * 4];
      f32x4 pc1 = *(const f32x4*)&Xc[w ^ 1][256 + lane * 4];
      sacc[0] += pc0;
      sacc[1] += pc1;
    }

    if (kt == t) {  // causal mask on diagonal tile
      #pragma unroll
      for (int kg2 = 0; kg2 < 2; ++kg2)
        #pragma unroll
        for (int r = 0; r < 4; ++r) {
          int key = kt * 32 + kg2 * 16 + l15;
          int row = q0 + 16 * pairIdx + quad * 4 + r;
          if (key > row) sacc[kg2][r] = -3e38f;
        }
    }

    // ---- online softmax (registers + DPP; identical in both pair waves) ----
    float mt[4], alpha[4];
    #pragma unroll
    for (int r = 0; r < 4; ++r)
      mt[r] = red16_max(fmaxf(sacc[0][r], sacc[1][r]));
    bool needAny = (mt[0] > m[0]) | (mt[1] > m[1]) | (mt[2] > m[2]) | (mt[3] > m[3]);
    unsigned long long bal = __ballot(needAny);
    if (bal) {
      #pragma unroll
      for (int r = 0; r < 4; ++r) {
        float mn = fmaxf(m[r], mt[r]);
        alpha[r] = __expf(m[r] - mn);
        m[r] = mn;
      }
    } else {
      #pragma unroll
      for (int r = 0; r < 4; ++r) alpha[r] = 1.0f;
    }
    float p[2][4];
    #pragma unroll
    for (int kg2 = 0; kg2 < 2; ++kg2)
      #pragma unroll
      for (int r = 0; r < 4; ++r) p[kg2][r] = __expf(sacc[kg2][r] - m[r]);
    #pragma unroll
    for (int r = 0; r < 4; ++r)
      l[r] = l[r] * alpha[r] + red16_sum(p[0][r] + p[1][r]);

    // ---- P: C-layout -> A-layout via wave-private LDS ----
    #pragma unroll
    for (int kg2 = 0; kg2 < 2; ++kg2)
      #pragma unroll
      for (int r = 0; r < 4; ++r)
        Pw[w][(quad * 4 + r) * 40 + kg2 * 16 + l15] = f2b_fast(p[kg2][r]);
    s16x8 pa = *(const s16x8*)&Pw[w][l15 * 40 + quad * 8];

    if (bal) {
      #pragma unroll
      for (int n = 0; n < 16; ++n)
        #pragma unroll
        for (int r = 0; r < 4; ++r) O[n][r] *= alpha[r];
    }

    // ---- PV: O[16 rows][cols wip*256..+255] += P(16x32) * V-half ----
    __builtin_amdgcn_s_setprio(1);
    #pragma unroll
    for (int dgl = 0; dgl < 16; ++dgl) {
      int dg = wip * 16 + dgl;
      s16x8 vf = *(const s16x8*)&ldsV[dg * 512 + lane * 8];
      O[dgl] = __builtin_amdgcn_mfma_f32_16x16x32_bf16(pa, vf, O[dgl], 0, 0, 0);
    }
    __builtin_amdgcn_s_setprio(0);
  }

  // ---- epilogue: wave writes its 16 rows x 256-col half ----
  float invl[4];
  #pragma unroll
  for (int r = 0; r < 4; ++r) invl[r] = 1.0f / l[r];
  float* ob = out + ((size_t)(bat * S_LEN + q0 + 16 * pairIdx)) * D_DIM + wip * 256;
  #pragma unroll
  for (int dgl = 0; dgl < 16; ++dgl)
    #pragma unroll
    for (int r = 0; r < 4; ++r)
      ob[(size_t)(quad * 4 + r) * D_DIM + dgl * 16 + l15] = O[dgl][r] * invl[r];
}

extern "C" void kernel_launch(void* const* d_in, const int* in_sizes, int n_in,
                              void* d_out, int out_size, void* d_ws, size_t ws_size,
                              hipStream_t stream) {
  (void)in_sizes; (void)n_in; (void)out_size; (void)ws_size;
  const float* x = (const float*)d_in[0];
  float* out = (float*)d_out;
  unsigned short* Kf = (unsigned short*)d_ws;                         // 16 MiB
  unsigned short* Vf = (unsigned short*)((char*)d_ws + (16u << 20));  // 16 MiB
  pack_kernel<<<2048, 256, 0, stream>>>(x, Kf, Vf);
  attn_kernel<<<512, 256, 0, stream>>>(Kf, Vf, out);
}

// Round 5
// 191.427 us; speedup vs baseline: 2.4338x; 1.1015x over previous
//
#include <hip/hip_runtime.h>

// CausalSelfAttention: B=8, S=2048, D=512, fp32 in/out, Q=K=V=x, no scale.
// Round 8: r7 (best: 139us attn) rescheduled — late drains + V in registers.
//   r7's gap analysis: T_tile ~5100cy vs ~2000cy computable; staging was
//   issued then immediately drained (gap=0), 3 barriers/tile. Changes:
//     - The exchange __syncthreads (after QK^T) already retires all waves'
//       K ds_reads -> it doubles as the ldsK overwrite guard. Stage K(t+1)
//       right AFTER it: ~600cy of softmax+Pw+PV sits between issue and the
//       loop-end drain (K 32KB L2 transfer ~585cy -> nearly hidden).
//       Barriers: 3 -> 2 per tile, neither drains a just-issued load.
//     - V never goes to LDS: PV reads V fragments verbatim and col-halves
//       are wave-private. V(t) lives in 16 s16x8 regs; V(t+1) is issued into
//       the SAME regs right after PV(t) consumed them (WAR pins the loads
//       after PV), drained at the loop-end barrier. Deletes 16 ds_read_b128
//       per tile; LDS 78.8KB -> 45KB.
//   Geometry unchanged from r7: 512 blocks x 256 thr (4 waves), block = one
//   32-row rowgroup, heavy/light sum-65 pairing; pair waves split QK^T by
//   D-half (partials summed via Xc exchange), PV split by col-half.
// ws: [0,16MiB) Kf, [16MiB,32MiB) Vf.

#define S_LEN 2048
#define D_DIM 512
#define BATCH_ELEMS 1048576  // 2 MiB bf16 per batch per array

typedef short s16x8 __attribute__((ext_vector_type(8)));
typedef float f32x4 __attribute__((ext_vector_type(4)));

__device__ __forceinline__ unsigned short f2b_rne(float f) {
  unsigned int u = __float_as_uint(f);
  return (unsigned short)((u + 0x7FFFu + ((u >> 16) & 1u)) >> 16);
}
__device__ __forceinline__ unsigned short f2b_fast(float f) {
  return (unsigned short)((__float_as_uint(f) + 0x8000u) >> 16);
}

template <int CTRL>
__device__ __forceinline__ float dppf(float x) {
  return __uint_as_float((unsigned)__builtin_amdgcn_update_dpp(
      0, (int)__float_as_uint(x), CTRL, 0xF, 0xF, true));
}
__device__ __forceinline__ float red16_max(float v) {
  v = fmaxf(v, dppf<0xB1>(v));   // xor 1
  v = fmaxf(v, dppf<0x4E>(v));   // xor 2
  v = fmaxf(v, dppf<0x124>(v));  // row_ror:4
  v = fmaxf(v, dppf<0x128>(v));  // row_ror:8
  return v;
}
__device__ __forceinline__ float red16_sum(float v) {
  v += dppf<0xB1>(v);
  v += dppf<0x4E>(v);
  v += dppf<0x124>(v);
  v += dppf<0x128>(v);
  return v;
}

// ---------------------------------------------------------------------------
// Prepass: pack x into Kf and Vf fragment order. 2048 blocks x 256 thr,
// 64x64 tile per block. A = [s][d] bf16, T = [d][s] bf16 (stride 72, 16B-al).
//   Kf[b][kg:128][db:16][lane:64][8]  elem = x[b][16*kg+l15][32*db+8*quad+j]
//   Vf[b][dg:32][kb:64][lane:64][8]   elem = x[b][32*kb+8*quad+j][16*dg+l15]
// ---------------------------------------------------------------------------
__global__ void pack_kernel(const float* __restrict__ x,
                            unsigned short* __restrict__ Kf,
                            unsigned short* __restrict__ Vf) {
  __shared__ unsigned short A[64 * 72];
  __shared__ unsigned short T[64 * 72];
  const int bid = blockIdx.x;
  const int b = bid >> 8, rem = bid & 255;
  const int s0 = (rem >> 3) * 64, d0 = (rem & 7) * 64;
  const int tid = threadIdx.x;

  // pass 1: load + convert, fill A[s][d]
  #pragma unroll
  for (int it = 0; it < 2; ++it) {
    int slot = it * 256 + tid;          // 0..511
    int row = slot >> 3, c = slot & 7;  // row 0..63, 8-col group
    const float* src = x + ((size_t)(b * S_LEN + s0 + row)) * D_DIM + d0 + c * 8;
    const float4 v0 = *(const float4*)(src);
    const float4 v1 = *(const float4*)(src + 4);
    s16x8 o;
    o[0] = (short)f2b_rne(v0.x); o[1] = (short)f2b_rne(v0.y);
    o[2] = (short)f2b_rne(v0.z); o[3] = (short)f2b_rne(v0.w);
    o[4] = (short)f2b_rne(v1.x); o[5] = (short)f2b_rne(v1.y);
    o[6] = (short)f2b_rne(v1.z); o[7] = (short)f2b_rne(v1.w);
    *(s16x8*)&A[row * 72 + c * 8] = o;
  }
  __syncthreads();

  // pass 2: transpose A -> T in 4x4 micro-blocks (vector b64 ops)
  {
    int sr = tid >> 4, sc = tid & 15;
    ushort4 a0 = *(const ushort4*)&A[(4 * sr + 0) * 72 + 4 * sc];
    ushort4 a1 = *(const ushort4*)&A[(4 * sr + 1) * 72 + 4 * sc];
    ushort4 a2 = *(const ushort4*)&A[(4 * sr + 2) * 72 + 4 * sc];
    ushort4 a3 = *(const ushort4*)&A[(4 * sr + 3) * 72 + 4 * sc];
    ushort4 t0; t0.x = a0.x; t0.y = a1.x; t0.z = a2.x; t0.w = a3.x;
    ushort4 t1; t1.x = a0.y; t1.y = a1.y; t1.z = a2.y; t1.w = a3.y;
    ushort4 t2; t2.x = a0.z; t2.y = a1.z; t2.z = a2.z; t2.w = a3.z;
    ushort4 t3; t3.x = a0.w; t3.y = a1.w; t3.z = a2.w; t3.w = a3.w;
    *(ushort4*)&T[(4 * sc + 0) * 72 + 4 * sr] = t0;
    *(ushort4*)&T[(4 * sc + 1) * 72 + 4 * sr] = t1;
    *(ushort4*)&T[(4 * sc + 2) * 72 + 4 * sr] = t2;
    *(ushort4*)&T[(4 * sc + 3) * 72 + 4 * sr] = t3;
  }
  __syncthreads();

  // pass 3: emit fragment blocks (each 64 consecutive threads write 1KB)
  #pragma unroll
  for (int it = 0; it < 2; ++it) {
    int slot = it * 256 + tid;
    int frag = slot >> 6;               // 0..7
    int lane = slot & 63;
    int l15 = lane & 15, quad = lane >> 4;
    int f1 = frag >> 1, f0 = frag & 1;  // f1: 0..3, f0: 0..1
    // Kf: kgl=f1 (16 rows), dbl=f0 (32 cols)
    {
      s16x8 val = *(const s16x8*)&A[(f1 * 16 + l15) * 72 + f0 * 32 + quad * 8];
      size_t kg = (size_t)(s0 >> 4) + f1, db = (size_t)(d0 >> 5) + f0;
      *(s16x8*)(Kf + (size_t)b * BATCH_ELEMS + (kg * 16 + db) * 512 + lane * 8) = val;
    }
    // Vf: dgl=f1 (16 cols), kbl=f0 (32 rows)
    {
      s16x8 val = *(const s16x8*)&T[(f1 * 16 + l15) * 72 + f0 * 32 + quad * 8];
      size_t dg = (size_t)(d0 >> 4) + f1, kb = (size_t)(s0 >> 5) + f0;
      *(s16x8*)(Vf + (size_t)b * BATCH_ELEMS + (dg * 64 + kb) * 512 + lane * 8) = val;
    }
  }
}

// ---------------------------------------------------------------------------
// Flash attention: 4 waves/block, split-D QK^T (partial exchange), split-col
// PV with V in registers. MFMA 16x16x32 layouts: A[m=l15][k=quad*8+j],
// B[k=quad*8+j][n=l15], C/D: col=l15, row=quad*4+reg.
// ---------------------------------------------------------------------------
__global__ __launch_bounds__(256, 2)
void attn_kernel(const unsigned short* __restrict__ Kf,
                 const unsigned short* __restrict__ Vf,
                 float* __restrict__ out) {
  __shared__ unsigned short ldsK[16384];  // 32 frag-blocks (kg2*16+db)*512+lane*8
  __shared__ float Xc[4][512];            // per-wave partial S (16x32 f32)
  __shared__ unsigned short Pw[4][16 * 40];

  const int bid = blockIdx.x;
  const int bat = bid & 7;
  const int t = (bid < 256) ? (63 - (bid >> 3)) : ((bid - 256) >> 3);
  const int q0 = t * 32;
  const int tid = threadIdx.x;
  const int w = tid >> 6;       // 0..3
  const int pairIdx = w >> 1;   // which 16-row half of the 32-row group
  const int wip = w & 1;        // which D-half (QK) / col-half (PV)
  const int lane = tid & 63;
  const int l15 = lane & 15, quad = lane >> 4;
  const size_t batOff = (size_t)bat * BATCH_ELEMS;

  // stage K tile (32KB) into ldsK, split across 4 waves (8 frag-blocks each)
  auto stageK = [&](int kt) {
    const unsigned short* ks =
        Kf + batOff + (size_t)kt * 16384 + (size_t)(w * 8) * 512 + lane * 8;
    #pragma unroll
    for (int i = 0; i < 8; ++i) {
      __builtin_amdgcn_global_load_lds(
          (const __attribute__((address_space(1))) unsigned int*)(ks + i * 512),
          (__attribute__((address_space(3))) unsigned int*)&ldsK[(w * 8 + i) * 512],
          16, 0, 0);
    }
  };

  // V fragments for this wave's col-half, kept in registers
  s16x8 vreg[16];
  auto loadV = [&](int kt) {
    const unsigned short* vb = Vf + batOff + (size_t)kt * 512 + lane * 8;
    #pragma unroll
    for (int dgl = 0; dgl < 16; ++dgl) {
      int dg = wip * 16 + dgl;
      vreg[dgl] = *(const s16x8*)(vb + (size_t)dg * 32768);
    }
  };

  // prologue: stage K(0), load V(0) + Q frags under the staging latency
  stageK(0);
  loadV(0);

  // Q fragments: rows q0+16*pairIdx..+15, d-half wip (db = wip*8 + i)
  s16x8 qf[8];
  {
    const unsigned short* qb =
        Kf + batOff + ((size_t)(2 * t + pairIdx) * 16 + wip * 8) * 512 + lane * 8;
    #pragma unroll
    for (int i = 0; i < 8; ++i) qf[i] = *(const s16x8*)(qb + i * 512);
  }

  f32x4 O[16];
  float m[4], l[4];
  #pragma unroll
  for (int n = 0; n < 16; ++n) O[n] = (f32x4){0.f, 0.f, 0.f, 0.f};
  #pragma unroll
  for (int r = 0; r < 4; ++r) { m[r] = -3e38f; l[r] = 0.f; }

  __syncthreads();  // K(0) in LDS, V(0)/qf in regs (implicit vmcnt drain)

  for (int kt = 0; kt <= t; ++kt) {
    // ---- QK^T partial over this wave's D-half: S_half[16 rows][32 keys] ----
    f32x4 sacc[2];
    sacc[0] = (f32x4){0.f, 0.f, 0.f, 0.f};
    sacc[1] = (f32x4){0.f, 0.f, 0.f, 0.f};
    __builtin_amdgcn_s_setprio(1);
    #pragma unroll
    for (int i = 0; i < 8; ++i) {
      int db = wip * 8 + i;
      s16x8 k0 = *(const s16x8*)&ldsK[db * 512 + lane * 8];
      s16x8 k1 = *(const s16x8*)&ldsK[(16 + db) * 512 + lane * 8];
      sacc[0] = __builtin_amdgcn_mfma_f32_16x16x32_bf16(qf[i], k0, sacc[0], 0, 0, 0);
      sacc[1] = __builtin_amdgcn_mfma_f32_16x16x32_bf16(qf[i], k1, sacc[1], 0, 0, 0);
    }
    __builtin_amdgcn_s_setprio(0);

    // ---- exchange partials within the pair; barrier doubles as K guard ----
    *(f32x4*)&Xc[w][lane * 4] = sacc[0];
    *(f32x4*)&Xc[w][256 + lane * 4] = sacc[1];
    __syncthreads();  // publishes partials AND retires all waves' K reads
    {
      f32x4 pc0 = *(const f32x4*)&Xc[w ^ 1][lane * 4];
      f32x4 pc1 = *(const f32x4*)&Xc[w ^ 1][256 + lane * 4];
      sacc[0] += pc0;
      sacc[1] += pc1;
    }

    // ---- stage K(t+1) now: ~600cy of softmax+Pw+PV hides the transfer ----
    if (kt < t) stageK(kt + 1);

    if (kt == t) {  // causal mask on diagonal tile
      #pragma unroll
      for (int kg2 = 0; kg2 < 2; ++kg2)
        #pragma unroll
        for (int r = 0; r < 4; ++r) {
          int key = kt * 32 + kg2 * 16 + l15;
          int row = q0 + 16 * pairIdx + quad * 4 + r;
          if (key > row) sacc[kg2][r] = -3e38f;
        }
    }

    // ---- online softmax (registers + DPP; identical in both pair waves) ----
    float mt[4], alpha[4];
    #pragma unroll
    for (int r = 0; r < 4; ++r)
      mt[r] = red16_max(fmaxf(sacc[0][r], sacc[1][r]));
    bool needAny = (mt[0] > m[0]) | (mt[1] > m[1]) | (mt[2] > m[2]) | (mt[3] > m[3]);
    unsigned long long bal = __ballot(needAny);
    if (bal) {
      #pragma unroll
      for (int r = 0; r < 4; ++r) {
        float mn = fmaxf(m[r], mt[r]);
        alpha[r] = __expf(m[r] - mn);
        m[r] = mn;
      }
    } else {
      #pragma unroll
      for (int r = 0; r < 4; ++r) alpha[r] = 1.0f;
    }
    float p[2][4];
    #pragma unroll
    for (int kg2 = 0; kg2 < 2; ++kg2)
      #pragma unroll
      for (int r = 0; r < 4; ++r) p[kg2][r] = __expf(sacc[kg2][r] - m[r]);
    #pragma unroll
    for (int r = 0; r < 4; ++r)
      l[r] = l[r] * alpha[r] + red16_sum(p[0][r] + p[1][r]);

    // ---- P: C-layout -> A-layout via wave-private LDS ----
    #pragma unroll
    for (int kg2 = 0; kg2 < 2; ++kg2)
      #pragma unroll
      for (int r = 0; r < 4; ++r)
        Pw[w][(quad * 4 + r) * 40 + kg2 * 16 + l15] = f2b_fast(p[kg2][r]);
    s16x8 pa = *(const s16x8*)&Pw[w][l15 * 40 + quad * 8];

    if (bal) {
      #pragma unroll
      for (int n = 0; n < 16; ++n)
        #pragma unroll
        for (int r = 0; r < 4; ++r) O[n][r] *= alpha[r];
    }

    // ---- PV: O[16 rows][cols wip*256..+255] += P(16x32) * V-half (regs) ----
    __builtin_amdgcn_s_setprio(1);
    #pragma unroll
    for (int dgl = 0; dgl < 16; ++dgl)
      O[dgl] = __builtin_amdgcn_mfma_f32_16x16x32_bf16(pa, vreg[dgl], O[dgl], 0, 0, 0);
    __builtin_amdgcn_s_setprio(0);

    // ---- refill vreg with V(t+1): WAR on vreg pins loads after PV ----
    if (kt < t) loadV(kt + 1);

    // loop-end barrier: K(t+1) visible + V(t+1) regs complete (vmcnt drain
    // lands ~600cy after K issue, right after V issue with 2-block overlap)
    __syncthreads();
  }

  // ---- epilogue: wave writes its 16 rows x 256-col half ----
  float invl[4];
  #pragma unroll
  for (int r = 0; r < 4; ++r) invl[r] = 1.0f / l[r];
  float* ob = out + ((size_t)(bat * S_LEN + q0 + 16 * pairIdx)) * D_DIM + wip * 256;
  #pragma unroll
  for (int dgl = 0; dgl < 16; ++dgl)
    #pragma unroll
    for (int r = 0; r < 4; ++r)
      ob[(size_t)(quad * 4 + r) * D_DIM + dgl * 16 + l15] = O[dgl][r] * invl[r];
}

extern "C" void kernel_launch(void* const* d_in, const int* in_sizes, int n_in,
                              void* d_out, int out_size, void* d_ws, size_t ws_size,
                              hipStream_t stream) {
  (void)in_sizes; (void)n_in; (void)out_size; (void)ws_size;
  const float* x = (const float*)d_in[0];
  float* out = (float*)d_out;
  unsigned short* Kf = (unsigned short*)d_ws;                         // 16 MiB
  unsigned short* Vf = (unsigned short*)((char*)d_ws + (16u << 20));  // 16 MiB
  pack_kernel<<<2048, 256, 0, stream>>>(x, Kf, Vf);
  attn_kernel<<<512, 256, 0, stream>>>(Kf, Vf, out);
}

// Round 6
// 180.464 us; speedup vs baseline: 2.5816x; 1.0607x over previous
//
#include <hip/hip_runtime.h>

// CausalSelfAttention: B=8, S=2048, D=512, fp32 in/out, Q=K=V=x, no scale.
// Round 9: 16-row blocks, 4-way D/col split, counted-vmcnt barriers.
//   r8 post-mortem: 121.5us but spilled (WRITE 32768->43384KB scratch) — the
//   2-wave split's vreg(64)+qf(32)+O(64) exceeds the 128-VGPR arch split at
//   2 blocks/CU; and the loop-end __syncthreads drained vmcnt(0), exposing
//   the just-issued V loads' full latency every tile. Changes:
//     - 1024 blocks x 256 thr (4 waves); block = ONE 16-row group. QK^T
//       split 4-ways by D-quarter (qf[4], 8 MFMA/wave); partial S summed via
//       fixed-order 4-way LDS exchange (bit-identical in all waves). PV
//       split 4-ways by col-quarter (vreg[8], O[8], 8 MFMA/wave). Registers
//       ~140 incl AGPR -> no spill. No MFMA duplication (only softmax VALU
//       is duplicated, parallel across waves).
//     - exchange barrier: s_waitcnt lgkmcnt(0) + raw s_barrier (+sched_bar) —
//       V loads stay outstanding across it.
//     - loop-end barrier: s_waitcnt vmcnt(8) + raw s_barrier — waits only
//       the 8 K-staging ops (issued first); the 8 newer V loads stay in
//       flight, consumed via compiler-inserted wait at next tile's PV
//       (~700cy later). V latency never drained explicitly.
//     - dispatch in descending-tile LPT order: rg = 127-(bid>>3); 4 blocks/
//       CU greedy -> ~130 tiles/CU balanced. bat=bid&7 keeps batch->XCD L2
//       affinity (4MiB Kf+Vf per batch fits one XCD L2).
// ws: [0,16MiB) Kf, [16MiB,32MiB) Vf.

#define S_LEN 2048
#define D_DIM 512
#define BATCH_ELEMS 1048576  // 2 MiB bf16 per batch per array

typedef short s16x8 __attribute__((ext_vector_type(8)));
typedef float f32x4 __attribute__((ext_vector_type(4)));

__device__ __forceinline__ unsigned short f2b_rne(float f) {
  unsigned int u = __float_as_uint(f);
  return (unsigned short)((u + 0x7FFFu + ((u >> 16) & 1u)) >> 16);
}
__device__ __forceinline__ unsigned short f2b_fast(float f) {
  return (unsigned short)((__float_as_uint(f) + 0x8000u) >> 16);
}

template <int CTRL>
__device__ __forceinline__ float dppf(float x) {
  return __uint_as_float((unsigned)__builtin_amdgcn_update_dpp(
      0, (int)__float_as_uint(x), CTRL, 0xF, 0xF, true));
}
__device__ __forceinline__ float red16_max(float v) {
  v = fmaxf(v, dppf<0xB1>(v));   // xor 1
  v = fmaxf(v, dppf<0x4E>(v));   // xor 2
  v = fmaxf(v, dppf<0x124>(v));  // row_ror:4
  v = fmaxf(v, dppf<0x128>(v));  // row_ror:8
  return v;
}
__device__ __forceinline__ float red16_sum(float v) {
  v += dppf<0xB1>(v);
  v += dppf<0x4E>(v);
  v += dppf<0x124>(v);
  v += dppf<0x128>(v);
  return v;
}

// ---------------------------------------------------------------------------
// Prepass: pack x into Kf and Vf fragment order. 2048 blocks x 256 thr,
// 64x64 tile per block. A = [s][d] bf16, T = [d][s] bf16 (stride 72, 16B-al).
//   Kf[b][kg:128][db:16][lane:64][8]  elem = x[b][16*kg+l15][32*db+8*quad+j]
//   Vf[b][dg:32][kb:64][lane:64][8]   elem = x[b][32*kb+8*quad+j][16*dg+l15]
// ---------------------------------------------------------------------------
__global__ void pack_kernel(const float* __restrict__ x,
                            unsigned short* __restrict__ Kf,
                            unsigned short* __restrict__ Vf) {
  __shared__ unsigned short A[64 * 72];
  __shared__ unsigned short T[64 * 72];
  const int bid = blockIdx.x;
  const int b = bid >> 8, rem = bid & 255;
  const int s0 = (rem >> 3) * 64, d0 = (rem & 7) * 64;
  const int tid = threadIdx.x;

  // pass 1: load + convert, fill A[s][d]
  #pragma unroll
  for (int it = 0; it < 2; ++it) {
    int slot = it * 256 + tid;          // 0..511
    int row = slot >> 3, c = slot & 7;  // row 0..63, 8-col group
    const float* src = x + ((size_t)(b * S_LEN + s0 + row)) * D_DIM + d0 + c * 8;
    const float4 v0 = *(const float4*)(src);
    const float4 v1 = *(const float4*)(src + 4);
    s16x8 o;
    o[0] = (short)f2b_rne(v0.x); o[1] = (short)f2b_rne(v0.y);
    o[2] = (short)f2b_rne(v0.z); o[3] = (short)f2b_rne(v0.w);
    o[4] = (short)f2b_rne(v1.x); o[5] = (short)f2b_rne(v1.y);
    o[6] = (short)f2b_rne(v1.z); o[7] = (short)f2b_rne(v1.w);
    *(s16x8*)&A[row * 72 + c * 8] = o;
  }
  __syncthreads();

  // pass 2: transpose A -> T in 4x4 micro-blocks (vector b64 ops)
  {
    int sr = tid >> 4, sc = tid & 15;
    ushort4 a0 = *(const ushort4*)&A[(4 * sr + 0) * 72 + 4 * sc];
    ushort4 a1 = *(const ushort4*)&A[(4 * sr + 1) * 72 + 4 * sc];
    ushort4 a2 = *(const ushort4*)&A[(4 * sr + 2) * 72 + 4 * sc];
    ushort4 a3 = *(const ushort4*)&A[(4 * sr + 3) * 72 + 4 * sc];
    ushort4 t0; t0.x = a0.x; t0.y = a1.x; t0.z = a2.x; t0.w = a3.x;
    ushort4 t1; t1.x = a0.y; t1.y = a1.y; t1.z = a2.y; t1.w = a3.y;
    ushort4 t2; t2.x = a0.z; t2.y = a1.z; t2.z = a2.z; t2.w = a3.z;
    ushort4 t3; t3.x = a0.w; t3.y = a1.w; t3.z = a2.w; t3.w = a3.w;
    *(ushort4*)&T[(4 * sc + 0) * 72 + 4 * sr] = t0;
    *(ushort4*)&T[(4 * sc + 1) * 72 + 4 * sr] = t1;
    *(ushort4*)&T[(4 * sc + 2) * 72 + 4 * sr] = t2;
    *(ushort4*)&T[(4 * sc + 3) * 72 + 4 * sr] = t3;
  }
  __syncthreads();

  // pass 3: emit fragment blocks (each 64 consecutive threads write 1KB)
  #pragma unroll
  for (int it = 0; it < 2; ++it) {
    int slot = it * 256 + tid;
    int frag = slot >> 6;               // 0..7
    int lane = slot & 63;
    int l15 = lane & 15, quad = lane >> 4;
    int f1 = frag >> 1, f0 = frag & 1;  // f1: 0..3, f0: 0..1
    // Kf: kgl=f1 (16 rows), dbl=f0 (32 cols)
    {
      s16x8 val = *(const s16x8*)&A[(f1 * 16 + l15) * 72 + f0 * 32 + quad * 8];
      size_t kg = (size_t)(s0 >> 4) + f1, db = (size_t)(d0 >> 5) + f0;
      *(s16x8*)(Kf + (size_t)b * BATCH_ELEMS + (kg * 16 + db) * 512 + lane * 8) = val;
    }
    // Vf: dgl=f1 (16 cols), kbl=f0 (32 rows)
    {
      s16x8 val = *(const s16x8*)&T[(f1 * 16 + l15) * 72 + f0 * 32 + quad * 8];
      size_t dg = (size_t)(d0 >> 4) + f1, kb = (size_t)(s0 >> 5) + f0;
      *(s16x8*)(Vf + (size_t)b * BATCH_ELEMS + (dg * 64 + kb) * 512 + lane * 8) = val;
    }
  }
}

// ---------------------------------------------------------------------------
// Flash attention: 16-row blocks, 4 waves quarter D (QK^T, exchange-summed)
// and quarter cols (PV, V in regs). MFMA 16x16x32 layouts:
// A[m=l15][k=quad*8+j], B[k=quad*8+j][n=l15], C/D: col=l15, row=quad*4+reg.
// ---------------------------------------------------------------------------
__global__ __launch_bounds__(256, 2)
void attn_kernel(const unsigned short* __restrict__ Kf,
                 const unsigned short* __restrict__ Vf,
                 float* __restrict__ out) {
  __shared__ unsigned short ldsK[16384];  // 32 frag-blocks (kg2*16+db)*512+lane*8
  __shared__ float Xc[4][512];            // per-wave partial S (16x32 f32)
  __shared__ unsigned short Pw[4][16 * 40];

  const int bid = blockIdx.x;
  const int bat = bid & 7;                // batch == XCD under round-robin
  const int rg = 127 - (bid >> 3);        // descending-tiles (LPT) order
  const int q0 = rg * 16;
  const int tmax = rg >> 1;               // tiles: tmax+1
  const int tid = threadIdx.x;
  const int w = tid >> 6;                 // 0..3: D-quarter / col-quarter
  const int lane = tid & 63;
  const int l15 = lane & 15, quad = lane >> 4;
  const size_t batOff = (size_t)bat * BATCH_ELEMS;

  // stage K tile (32KB) into ldsK, split across 4 waves (8 frag-blocks each)
  auto stageK = [&](int kt) {
    const unsigned short* ks =
        Kf + batOff + (size_t)kt * 16384 + (size_t)(w * 8) * 512 + lane * 8;
    #pragma unroll
    for (int i = 0; i < 8; ++i) {
      __builtin_amdgcn_global_load_lds(
          (const __attribute__((address_space(1))) unsigned int*)(ks + i * 512),
          (__attribute__((address_space(3))) unsigned int*)&ldsK[(w * 8 + i) * 512],
          16, 0, 0);
    }
  };

  // V fragments for this wave's col-quarter (cols w*128..+127), in registers
  s16x8 vreg[8];
  auto loadV = [&](int kt) {
    const unsigned short* vb = Vf + batOff + (size_t)kt * 512 + lane * 8;
    #pragma unroll
    for (int dgl = 0; dgl < 8; ++dgl)
      vreg[dgl] = *(const s16x8*)(vb + (size_t)(w * 8 + dgl) * 32768);
  };

  // prologue: stage K(0), load V(0) + Q frags under the staging latency
  stageK(0);
  loadV(0);

  // Q fragments: rows q0..q0+15, D-quarter w (db = w*4 + i)
  s16x8 qf[4];
  {
    const unsigned short* qb =
        Kf + batOff + ((size_t)rg * 16 + w * 4) * 512 + lane * 8;
    #pragma unroll
    for (int i = 0; i < 4; ++i) qf[i] = *(const s16x8*)(qb + i * 512);
  }

  f32x4 O[8];
  float m[4], l[4];
  #pragma unroll
  for (int n = 0; n < 8; ++n) O[n] = (f32x4){0.f, 0.f, 0.f, 0.f};
  #pragma unroll
  for (int r = 0; r < 4; ++r) { m[r] = -3e38f; l[r] = 0.f; }

  __syncthreads();  // K(0)/V(0)/qf ready (full drain OK once)

  for (int kt = 0;; ++kt) {
    // ---- QK^T partial over this wave's D-quarter: S_q[16 rows][32 keys] ----
    f32x4 sacc[2];
    sacc[0] = (f32x4){0.f, 0.f, 0.f, 0.f};
    sacc[1] = (f32x4){0.f, 0.f, 0.f, 0.f};
    __builtin_amdgcn_s_setprio(1);
    #pragma unroll
    for (int i = 0; i < 4; ++i) {
      int db = w * 4 + i;
      s16x8 k0 = *(const s16x8*)&ldsK[db * 512 + lane * 8];
      s16x8 k1 = *(const s16x8*)&ldsK[(16 + db) * 512 + lane * 8];
      sacc[0] = __builtin_amdgcn_mfma_f32_16x16x32_bf16(qf[i], k0, sacc[0], 0, 0, 0);
      sacc[1] = __builtin_amdgcn_mfma_f32_16x16x32_bf16(qf[i], k1, sacc[1], 0, 0, 0);
    }
    __builtin_amdgcn_s_setprio(0);

    // ---- 4-way exchange: publish partial, barrier (lgkm-only: V loads stay
    //      outstanding), fixed-order sum -> bit-identical full S in all waves
    *(f32x4*)&Xc[w][lane * 4] = sacc[0];
    *(f32x4*)&Xc[w][256 + lane * 4] = sacc[1];
    asm volatile("s_waitcnt lgkmcnt(0)" ::: "memory");
    __builtin_amdgcn_s_barrier();
    __builtin_amdgcn_sched_barrier(0);
    {
      f32x4 s0 = *(const f32x4*)&Xc[0][lane * 4];
      s0 += *(const f32x4*)&Xc[1][lane * 4];
      s0 += *(const f32x4*)&Xc[2][lane * 4];
      s0 += *(const f32x4*)&Xc[3][lane * 4];
      f32x4 s1 = *(const f32x4*)&Xc[0][256 + lane * 4];
      s1 += *(const f32x4*)&Xc[1][256 + lane * 4];
      s1 += *(const f32x4*)&Xc[2][256 + lane * 4];
      s1 += *(const f32x4*)&Xc[3][256 + lane * 4];
      sacc[0] = s0;
      sacc[1] = s1;
    }

    // ---- stage K(t+1) now: exchange barrier retired all waves' K reads;
    //      softmax+Pw+PV (~600cy) hides the L2 transfer ----
    if (kt < tmax) stageK(kt + 1);

    if (kt == tmax) {  // causal mask on diagonal tile
      #pragma unroll
      for (int kg2 = 0; kg2 < 2; ++kg2)
        #pragma unroll
        for (int r = 0; r < 4; ++r) {
          int key = kt * 32 + kg2 * 16 + l15;
          int row = q0 + quad * 4 + r;
          if (key > row) sacc[kg2][r] = -3e38f;
        }
    }

    // ---- online softmax (registers + DPP; identical in all 4 waves) ----
    float mt[4], alpha[4];
    #pragma unroll
    for (int r = 0; r < 4; ++r)
      mt[r] = red16_max(fmaxf(sacc[0][r], sacc[1][r]));
    bool needAny = (mt[0] > m[0]) | (mt[1] > m[1]) | (mt[2] > m[2]) | (mt[3] > m[3]);
    unsigned long long bal = __ballot(needAny);
    if (bal) {
      #pragma unroll
      for (int r = 0; r < 4; ++r) {
        float mn = fmaxf(m[r], mt[r]);
        alpha[r] = __expf(m[r] - mn);
        m[r] = mn;
      }
    } else {
      #pragma unroll
      for (int r = 0; r < 4; ++r) alpha[r] = 1.0f;
    }
    float p[2][4];
    #pragma unroll
    for (int kg2 = 0; kg2 < 2; ++kg2)
      #pragma unroll
      for (int r = 0; r < 4; ++r) p[kg2][r] = __expf(sacc[kg2][r] - m[r]);
    #pragma unroll
    for (int r = 0; r < 4; ++r)
      l[r] = l[r] * alpha[r] + red16_sum(p[0][r] + p[1][r]);

    // ---- P: C-layout -> A-layout via wave-private LDS ----
    #pragma unroll
    for (int kg2 = 0; kg2 < 2; ++kg2)
      #pragma unroll
      for (int r = 0; r < 4; ++r)
        Pw[w][(quad * 4 + r) * 40 + kg2 * 16 + l15] = f2b_fast(p[kg2][r]);
    s16x8 pa = *(const s16x8*)&Pw[w][l15 * 40 + quad * 8];

    if (bal) {
      #pragma unroll
      for (int n = 0; n < 8; ++n)
        #pragma unroll
        for (int r = 0; r < 4; ++r) O[n][r] *= alpha[r];
    }

    // ---- PV: O[16 rows][cols w*128..+127] += P(16x32) * V-quarter (regs) ----
    __builtin_amdgcn_s_setprio(1);
    #pragma unroll
    for (int dgl = 0; dgl < 8; ++dgl)
      O[dgl] = __builtin_amdgcn_mfma_f32_16x16x32_bf16(pa, vreg[dgl], O[dgl], 0, 0, 0);
    __builtin_amdgcn_s_setprio(0);

    if (kt == tmax) break;

    // ---- refill vreg with V(t+1): WAR on vreg pins loads after PV ----
    loadV(kt + 1);

    // loop-end: wait ONLY the 8 K-staging ops (oldest); leave the 8 V loads
    // in flight — next tile's PV dependency wait covers them ~700cy later.
    asm volatile("s_waitcnt vmcnt(8)" ::: "memory");
    __builtin_amdgcn_s_barrier();
    __builtin_amdgcn_sched_barrier(0);
  }

  // ---- epilogue: wave writes its 16 rows x 128-col quarter ----
  float invl[4];
  #pragma unroll
  for (int r = 0; r < 4; ++r) invl[r] = 1.0f / l[r];
  float* ob = out + ((size_t)(bat * S_LEN + q0)) * D_DIM + w * 128;
  #pragma unroll
  for (int dgl = 0; dgl < 8; ++dgl)
    #pragma unroll
    for (int r = 0; r < 4; ++r)
      ob[(size_t)(quad * 4 + r) * D_DIM + dgl * 16 + l15] = O[dgl][r] * invl[r];
}

extern "C" void kernel_launch(void* const* d_in, const int* in_sizes, int n_in,
                              void* d_out, int out_size, void* d_ws, size_t ws_size,
                              hipStream_t stream) {
  (void)in_sizes; (void)n_in; (void)out_size; (void)ws_size;
  const float* x = (const float*)d_in[0];
  float* out = (float*)d_out;
  unsigned short* Kf = (unsigned short*)d_ws;                         // 16 MiB
  unsigned short* Vf = (unsigned short*)((char*)d_ws + (16u << 20));  // 16 MiB
  pack_kernel<<<2048, 256, 0, stream>>>(x, Kf, Vf);
  attn_kernel<<<1024, 256, 0, stream>>>(Kf, Vf, out);
}

// Round 7
// 170.330 us; speedup vs baseline: 2.7352x; 1.0595x over previous
//
#include <hip/hip_runtime.h>

// CausalSelfAttention: B=8, S=2048, D=512, fp32 in/out, Q=K=V=x, no scale.
// Round 10: K in registers — LDS used ONLY for the exchange + P transpose.
//   r9 analysis: T_tile 2063cy ~= LDS-port demand (2 blocks x 4 waves x ~19
//   b128 x 12cy + 32KB gload_lds DMA writes) -> r9 was LDS-PORT-bound, which
//   is why MfmaUtil(13%)/VALU(50%) both sat below any wall. Fix: the prepass
//   fragment layout makes K loads plain 1KB coalesced global loads, so keep
//   each wave's D-quarter of K in regs (kreg[8]), prefetched a full phase
//   ahead (issued right after QK consumes them, ~1200cy before next use) —
//   the exact pattern already proven for V. Deletes per tile: 8 QK ds_reads,
//   8 gload_lds DMA writes, the staging barrier. Xc parity double-buffer
//   (Xc[kt&1]) removes the loop-end barrier: ONE barrier per tile.
//   Differs from failed r6 direct-L2: prefetch distance + 8 waves/CU.
//   Geometry as r9: 1024 blocks x 256 thr (4 waves), block = one 16-row
//   group; QK split by D-quarter (partials summed via exchange, fixed order
//   -> bit-identical S in all waves); PV split by col-quarter, V in regs.
//   LPT descending rg; bat=bid&7 -> batch==XCD L2 affinity.
// ws: [0,16MiB) Kf, [16MiB,32MiB) Vf.

#define S_LEN 2048
#define D_DIM 512
#define BATCH_ELEMS 1048576  // 2 MiB bf16 per batch per array

typedef short s16x8 __attribute__((ext_vector_type(8)));
typedef float f32x4 __attribute__((ext_vector_type(4)));

__device__ __forceinline__ unsigned short f2b_rne(float f) {
  unsigned int u = __float_as_uint(f);
  return (unsigned short)((u + 0x7FFFu + ((u >> 16) & 1u)) >> 16);
}
__device__ __forceinline__ unsigned short f2b_fast(float f) {
  return (unsigned short)((__float_as_uint(f) + 0x8000u) >> 16);
}

template <int CTRL>
__device__ __forceinline__ float dppf(float x) {
  return __uint_as_float((unsigned)__builtin_amdgcn_update_dpp(
      0, (int)__float_as_uint(x), CTRL, 0xF, 0xF, true));
}
__device__ __forceinline__ float red16_max(float v) {
  v = fmaxf(v, dppf<0xB1>(v));   // xor 1
  v = fmaxf(v, dppf<0x4E>(v));   // xor 2
  v = fmaxf(v, dppf<0x124>(v));  // row_ror:4
  v = fmaxf(v, dppf<0x128>(v));  // row_ror:8
  return v;
}
__device__ __forceinline__ float red16_sum(float v) {
  v += dppf<0xB1>(v);
  v += dppf<0x4E>(v);
  v += dppf<0x124>(v);
  v += dppf<0x128>(v);
  return v;
}

// ---------------------------------------------------------------------------
// Prepass: pack x into Kf and Vf fragment order. 2048 blocks x 256 thr,
// 64x64 tile per block. A = [s][d] bf16, T = [d][s] bf16 (stride 72, 16B-al).
//   Kf[b][kg:128][db:16][lane:64][8]  elem = x[b][16*kg+l15][32*db+8*quad+j]
//   Vf[b][dg:32][kb:64][lane:64][8]   elem = x[b][32*kb+8*quad+j][16*dg+l15]
// ---------------------------------------------------------------------------
__global__ void pack_kernel(const float* __restrict__ x,
                            unsigned short* __restrict__ Kf,
                            unsigned short* __restrict__ Vf) {
  __shared__ unsigned short A[64 * 72];
  __shared__ unsigned short T[64 * 72];
  const int bid = blockIdx.x;
  const int b = bid >> 8, rem = bid & 255;
  const int s0 = (rem >> 3) * 64, d0 = (rem & 7) * 64;
  const int tid = threadIdx.x;

  // pass 1: load + convert, fill A[s][d]
  #pragma unroll
  for (int it = 0; it < 2; ++it) {
    int slot = it * 256 + tid;          // 0..511
    int row = slot >> 3, c = slot & 7;  // row 0..63, 8-col group
    const float* src = x + ((size_t)(b * S_LEN + s0 + row)) * D_DIM + d0 + c * 8;
    const float4 v0 = *(const float4*)(src);
    const float4 v1 = *(const float4*)(src + 4);
    s16x8 o;
    o[0] = (short)f2b_rne(v0.x); o[1] = (short)f2b_rne(v0.y);
    o[2] = (short)f2b_rne(v0.z); o[3] = (short)f2b_rne(v0.w);
    o[4] = (short)f2b_rne(v1.x); o[5] = (short)f2b_rne(v1.y);
    o[6] = (short)f2b_rne(v1.z); o[7] = (short)f2b_rne(v1.w);
    *(s16x8*)&A[row * 72 + c * 8] = o;
  }
  __syncthreads();

  // pass 2: transpose A -> T in 4x4 micro-blocks (vector b64 ops)
  {
    int sr = tid >> 4, sc = tid & 15;
    ushort4 a0 = *(const ushort4*)&A[(4 * sr + 0) * 72 + 4 * sc];
    ushort4 a1 = *(const ushort4*)&A[(4 * sr + 1) * 72 + 4 * sc];
    ushort4 a2 = *(const ushort4*)&A[(4 * sr + 2) * 72 + 4 * sc];
    ushort4 a3 = *(const ushort4*)&A[(4 * sr + 3) * 72 + 4 * sc];
    ushort4 t0; t0.x = a0.x; t0.y = a1.x; t0.z = a2.x; t0.w = a3.x;
    ushort4 t1; t1.x = a0.y; t1.y = a1.y; t1.z = a2.y; t1.w = a3.y;
    ushort4 t2; t2.x = a0.z; t2.y = a1.z; t2.z = a2.z; t2.w = a3.z;
    ushort4 t3; t3.x = a0.w; t3.y = a1.w; t3.z = a2.w; t3.w = a3.w;
    *(ushort4*)&T[(4 * sc + 0) * 72 + 4 * sr] = t0;
    *(ushort4*)&T[(4 * sc + 1) * 72 + 4 * sr] = t1;
    *(ushort4*)&T[(4 * sc + 2) * 72 + 4 * sr] = t2;
    *(ushort4*)&T[(4 * sc + 3) * 72 + 4 * sr] = t3;
  }
  __syncthreads();

  // pass 3: emit fragment blocks (each 64 consecutive threads write 1KB)
  #pragma unroll
  for (int it = 0; it < 2; ++it) {
    int slot = it * 256 + tid;
    int frag = slot >> 6;               // 0..7
    int lane = slot & 63;
    int l15 = lane & 15, quad = lane >> 4;
    int f1 = frag >> 1, f0 = frag & 1;  // f1: 0..3, f0: 0..1
    // Kf: kgl=f1 (16 rows), dbl=f0 (32 cols)
    {
      s16x8 val = *(const s16x8*)&A[(f1 * 16 + l15) * 72 + f0 * 32 + quad * 8];
      size_t kg = (size_t)(s0 >> 4) + f1, db = (size_t)(d0 >> 5) + f0;
      *(s16x8*)(Kf + (size_t)b * BATCH_ELEMS + (kg * 16 + db) * 512 + lane * 8) = val;
    }
    // Vf: dgl=f1 (16 cols), kbl=f0 (32 rows)
    {
      s16x8 val = *(const s16x8*)&T[(f1 * 16 + l15) * 72 + f0 * 32 + quad * 8];
      size_t dg = (size_t)(d0 >> 4) + f1, kb = (size_t)(s0 >> 5) + f0;
      *(s16x8*)(Vf + (size_t)b * BATCH_ELEMS + (dg * 64 + kb) * 512 + lane * 8) = val;
    }
  }
}

// ---------------------------------------------------------------------------
// Flash attention: 16-row blocks, 4 waves quarter D (QK^T from K-in-regs,
// exchange-summed) and quarter cols (PV, V in regs). LDS: exchange + P only.
// MFMA 16x16x32 layouts: A[m=l15][k=quad*8+j], B[k=quad*8+j][n=l15],
// C/D: col=l15, row=quad*4+reg.
// ---------------------------------------------------------------------------
__global__ __launch_bounds__(256, 2)
void attn_kernel(const unsigned short* __restrict__ Kf,
                 const unsigned short* __restrict__ Vf,
                 float* __restrict__ out) {
  __shared__ float Xc[2][4][512];         // parity-dbuf per-wave partial S
  __shared__ unsigned short Pw[4][16 * 40];

  const int bid = blockIdx.x;
  const int bat = bid & 7;                // batch == XCD under round-robin
  const int rg = 127 - (bid >> 3);        // descending-tiles (LPT) order
  const int q0 = rg * 16;
  const int tmax = rg >> 1;               // tiles: tmax+1
  const int tid = threadIdx.x;
  const int w = tid >> 6;                 // 0..3: D-quarter / col-quarter
  const int lane = tid & 63;
  const int l15 = lane & 15, quad = lane >> 4;
  const size_t batOff = (size_t)bat * BATCH_ELEMS;

  // K fragments for this wave's D-quarter (db = w*4..w*4+3, both key halves)
  s16x8 kreg[8];
  auto loadK = [&](int kt) {
    const unsigned short* kb = Kf + batOff + (size_t)kt * 16384 + lane * 8;
    #pragma unroll
    for (int i = 0; i < 4; ++i) {
      kreg[i]     = *(const s16x8*)(kb + (size_t)(w * 4 + i) * 512);        // keys 0-15
      kreg[4 + i] = *(const s16x8*)(kb + (size_t)(16 + w * 4 + i) * 512);   // keys 16-31
    }
  };

  // V fragments for this wave's col-quarter (cols w*128..+127), in registers
  s16x8 vreg[8];
  auto loadV = [&](int kt) {
    const unsigned short* vb = Vf + batOff + (size_t)kt * 512 + lane * 8;
    #pragma unroll
    for (int dgl = 0; dgl < 8; ++dgl)
      vreg[dgl] = *(const s16x8*)(vb + (size_t)(w * 8 + dgl) * 32768);
  };

  // prologue: K(0), V(0), Q fragments (latency exposed once)
  loadK(0);
  loadV(0);

  // Q fragments: rows q0..q0+15, D-quarter w (db = w*4 + i)
  s16x8 qf[4];
  {
    const unsigned short* qb =
        Kf + batOff + ((size_t)rg * 16 + w * 4) * 512 + lane * 8;
    #pragma unroll
    for (int i = 0; i < 4; ++i) qf[i] = *(const s16x8*)(qb + i * 512);
  }

  f32x4 O[8];
  float m[4], l[4];
  #pragma unroll
  for (int n = 0; n < 8; ++n) O[n] = (f32x4){0.f, 0.f, 0.f, 0.f};
  #pragma unroll
  for (int r = 0; r < 4; ++r) { m[r] = -3e38f; l[r] = 0.f; }

  for (int kt = 0;; ++kt) {
    const int p = kt & 1;

    // ---- QK^T partial over this wave's D-quarter (K from regs) ----
    f32x4 sacc[2];
    sacc[0] = (f32x4){0.f, 0.f, 0.f, 0.f};
    sacc[1] = (f32x4){0.f, 0.f, 0.f, 0.f};
    __builtin_amdgcn_s_setprio(1);
    #pragma unroll
    for (int i = 0; i < 4; ++i) {
      sacc[0] = __builtin_amdgcn_mfma_f32_16x16x32_bf16(qf[i], kreg[i], sacc[0], 0, 0, 0);
      sacc[1] = __builtin_amdgcn_mfma_f32_16x16x32_bf16(qf[i], kreg[4 + i], sacc[1], 0, 0, 0);
    }
    __builtin_amdgcn_s_setprio(0);

    // ---- prefetch K(t+1) into kreg (WAR pins after QK); lands during
    //      exchange+softmax+PV, consumed next tile (~1200cy later) ----
    if (kt < tmax) loadK(kt + 1);

    // ---- 4-way exchange: publish partial, ONE barrier, fixed-order sum ----
    *(f32x4*)&Xc[p][w][lane * 4] = sacc[0];
    *(f32x4*)&Xc[p][w][256 + lane * 4] = sacc[1];
    asm volatile("s_waitcnt lgkmcnt(0)" ::: "memory");
    __builtin_amdgcn_s_barrier();
    __builtin_amdgcn_sched_barrier(0);
    {
      f32x4 s0 = *(const f32x4*)&Xc[p][0][lane * 4];
      s0 += *(const f32x4*)&Xc[p][1][lane * 4];
      s0 += *(const f32x4*)&Xc[p][2][lane * 4];
      s0 += *(const f32x4*)&Xc[p][3][lane * 4];
      f32x4 s1 = *(const f32x4*)&Xc[p][0][256 + lane * 4];
      s1 += *(const f32x4*)&Xc[p][1][256 + lane * 4];
      s1 += *(const f32x4*)&Xc[p][2][256 + lane * 4];
      s1 += *(const f32x4*)&Xc[p][3][256 + lane * 4];
      sacc[0] = s0;
      sacc[1] = s1;
    }

    if (kt == tmax) {  // causal mask on diagonal tile
      #pragma unroll
      for (int kg2 = 0; kg2 < 2; ++kg2)
        #pragma unroll
        for (int r = 0; r < 4; ++r) {
          int key = kt * 32 + kg2 * 16 + l15;
          int row = q0 + quad * 4 + r;
          if (key > row) sacc[kg2][r] = -3e38f;
        }
    }

    // ---- online softmax (registers + DPP; identical in all 4 waves) ----
    float mt[4], alpha[4];
    #pragma unroll
    for (int r = 0; r < 4; ++r)
      mt[r] = red16_max(fmaxf(sacc[0][r], sacc[1][r]));
    bool needAny = (mt[0] > m[0]) | (mt[1] > m[1]) | (mt[2] > m[2]) | (mt[3] > m[3]);
    unsigned long long bal = __ballot(needAny);
    if (bal) {
      #pragma unroll
      for (int r = 0; r < 4; ++r) {
        float mn = fmaxf(m[r], mt[r]);
        alpha[r] = __expf(m[r] - mn);
        m[r] = mn;
      }
    } else {
      #pragma unroll
      for (int r = 0; r < 4; ++r) alpha[r] = 1.0f;
    }
    float p2[2][4];
    #pragma unroll
    for (int kg2 = 0; kg2 < 2; ++kg2)
      #pragma unroll
      for (int r = 0; r < 4; ++r) p2[kg2][r] = __expf(sacc[kg2][r] - m[r]);
    #pragma unroll
    for (int r = 0; r < 4; ++r)
      l[r] = l[r] * alpha[r] + red16_sum(p2[0][r] + p2[1][r]);

    // ---- P: C-layout -> A-layout via wave-private LDS ----
    #pragma unroll
    for (int kg2 = 0; kg2 < 2; ++kg2)
      #pragma unroll
      for (int r = 0; r < 4; ++r)
        Pw[w][(quad * 4 + r) * 40 + kg2 * 16 + l15] = f2b_fast(p2[kg2][r]);
    s16x8 pa = *(const s16x8*)&Pw[w][l15 * 40 + quad * 8];

    if (bal) {
      #pragma unroll
      for (int n = 0; n < 8; ++n)
        #pragma unroll
        for (int r = 0; r < 4; ++r) O[n][r] *= alpha[r];
    }

    // ---- PV: O[16 rows][cols w*128..+127] += P(16x32) * V-quarter (regs) ----
    __builtin_amdgcn_s_setprio(1);
    #pragma unroll
    for (int dgl = 0; dgl < 8; ++dgl)
      O[dgl] = __builtin_amdgcn_mfma_f32_16x16x32_bf16(pa, vreg[dgl], O[dgl], 0, 0, 0);
    __builtin_amdgcn_s_setprio(0);

    if (kt == tmax) break;

    // ---- prefetch V(t+1) (WAR pins after PV); no loop-end barrier needed:
    //      Xc parity gives 2-tile reuse distance, barrier(t+1) orders it ----
    loadV(kt + 1);
  }

  // ---- epilogue: wave writes its 16 rows x 128-col quarter ----
  float invl[4];
  #pragma unroll
  for (int r = 0; r < 4; ++r) invl[r] = 1.0f / l[r];
  float* ob = out + ((size_t)(bat * S_LEN + q0)) * D_DIM + w * 128;
  #pragma unroll
  for (int dgl = 0; dgl < 8; ++dgl)
    #pragma unroll
    for (int r = 0; r < 4; ++r)
      ob[(size_t)(quad * 4 + r) * D_DIM + dgl * 16 + l15] = O[dgl][r] * invl[r];
}

extern "C" void kernel_launch(void* const* d_in, const int* in_sizes, int n_in,
                              void* d_out, int out_size, void* d_ws, size_t ws_size,
                              hipStream_t stream) {
  (void)in_sizes; (void)n_in; (void)out_size; (void)ws_size;
  const float* x = (const float*)d_in[0];
  float* out = (float*)d_out;
  unsigned short* Kf = (unsigned short*)d_ws;                         // 16 MiB
  unsigned short* Vf = (unsigned short*)((char*)d_ws + (16u << 20));  // 16 MiB
  pack_kernel<<<2048, 256, 0, stream>>>(x, Kf, Vf);
  attn_kernel<<<1024, 256, 0, stream>>>(Kf, Vf, out);
}